// Round 6
// baseline (361.943 us; speedup 1.0000x reference)
//
#include <hip/hip_runtime.h>
#include <cmath>

// ---------------------------------------------------------------------------
// SConvNetBlock: LN1 -> SiLU -> complex-decay scan -> *sc_lin -> +res
//                -> LN2 -> FFN(GEMM+SiLU+GEMM) -> +res
// Round-6:
//  * GEMM1 (8192x4096x1024): 32x32x16 MFMA 128x128 2-barrier (r5, 102us).
//  * GEMM2 (8192x1024x4096): 16x16x32 MFMA 128x128 2-barrier (r4 kernel,
//    0 LDS conflicts; 32x32 variant regressed this fetch-critical GEMM).
//  * Scans vectorized: float4 over d (4 channels/thread), CHUNKS=128.
//  * ln_stats + inline LN1+SiLU recompute (h eliminated), ln2 separate.
// ---------------------------------------------------------------------------

#define DIMD 1024
#define FFD  4096
#define BATCH 4
#define SEQL 2048
#define MROWS (BATCH*SEQL)      // 8192
#define EPSF 1e-5f
#define CHUNKS2 128
#define CLEN2 (SEQL/CHUNKS2)    // 16

typedef __attribute__((ext_vector_type(8)))  _Float16 half8;
typedef __attribute__((ext_vector_type(4)))  _Float16 half4;
typedef __attribute__((ext_vector_type(4)))  float    floatx4;
typedef __attribute__((ext_vector_type(16))) float    floatx16;

// ---- workspace layout (bytes) ----
#define ST_OFF   0u                       // st  float2 [8192]         64 KB
#define E_OFF    1048576u                 // e   float2 [4][128][1024]   4 MB
#define SV_OFF   5242880u                 // sv  float2 [4][128][1024]   4 MB
#define H2_OFF   35651584u                // h2  fp16 [8192][1024]     16 MB
#define W1H_OFF  52428800u                // w1h fp16 [4096][1024]      8 MB
#define W2H_OFF  60817408u                // w2h fp16 [1024][4096]      8 MB
#define Y1_OFF   69206016u                // y1  fp16 [8192][4096]     64 MB

__device__ __forceinline__ void load_lds16(const _Float16* g, _Float16* l) {
    __builtin_amdgcn_global_load_lds(
        (const __attribute__((address_space(1))) unsigned int*)g,
        (__attribute__((address_space(3))) unsigned int*)l,
        16, 0, 0);
}

__global__ __launch_bounds__(256)
void cast_f32_f16(const float* __restrict__ src, _Float16* __restrict__ dst) {
    int i = (blockIdx.x * 256 + threadIdx.x) * 4;
    float4 v = *(const float4*)(src + i);
    half4 o;
    o.x = (_Float16)v.x; o.y = (_Float16)v.y; o.z = (_Float16)v.z; o.w = (_Float16)v.w;
    *(half4*)(dst + i) = o;
}

// per-row LN statistics: st[row] = (mu, rsqrt(var+eps))
__global__ __launch_bounds__(256)
void ln_stats(const float* __restrict__ x, float2* __restrict__ st) {
    const size_t row = blockIdx.x;
    const int tid = threadIdx.x;
    float4 v = *(const float4*)(x + row * DIMD + tid * 4);
    float s = (v.x + v.y) + (v.z + v.w);
    float q = (v.x * v.x + v.y * v.y) + (v.z * v.z + v.w * v.w);
    #pragma unroll
    for (int off = 32; off; off >>= 1) {
        s += __shfl_down(s, off, 64);
        q += __shfl_down(q, off, 64);
    }
    __shared__ float red[8];
    if (!(tid & 63)) { red[tid >> 6] = s; red[4 + (tid >> 6)] = q; }
    __syncthreads();
    if (tid == 0) {
        s = (red[0] + red[1]) + (red[2] + red[3]);
        q = (red[4] + red[5]) + (red[6] + red[7]);
        const float mu = s * (1.f / DIMD);
        const float rs = rsqrtf(q * (1.f / DIMD) - mu * mu + EPSF);
        st[row] = make_float2(mu, rs);
    }
}

// LN2: out fp16 = LN(x)
__global__ __launch_bounds__(256)
void ln_kernel(const float* __restrict__ x, const float* __restrict__ w,
               const float* __restrict__ b, _Float16* __restrict__ oh) {
    const size_t row = blockIdx.x;
    const int tid = threadIdx.x;
    float4 v = *(const float4*)(x + row * DIMD + tid * 4);
    float s = (v.x + v.y) + (v.z + v.w);
    float q = (v.x * v.x + v.y * v.y) + (v.z * v.z + v.w * v.w);
    #pragma unroll
    for (int off = 32; off; off >>= 1) {
        s += __shfl_down(s, off, 64);
        q += __shfl_down(q, off, 64);
    }
    __shared__ float red[8];
    if (!(tid & 63)) { red[tid >> 6] = s; red[4 + (tid >> 6)] = q; }
    __syncthreads();
    s = (red[0] + red[1]) + (red[2] + red[3]);
    q = (red[4] + red[5]) + (red[6] + red[7]);
    const float mu = s * (1.f / DIMD);
    const float rs = rsqrtf(q * (1.f / DIMD) - mu * mu + EPSF);
    float4 wv = *(const float4*)(w + tid * 4);
    float4 bv = *(const float4*)(b + tid * 4);
    half4 hv;
    hv.x = (_Float16)((v.x - mu) * rs * wv.x + bv.x);
    hv.y = (_Float16)((v.y - mu) * rs * wv.y + bv.y);
    hv.z = (_Float16)((v.z - mu) * rs * wv.z + bv.z);
    hv.w = (_Float16)((v.w - mu) * rs * wv.w + bv.w);
    *(half4*)(oh + row * DIMD + tid * 4) = hv;
}

__device__ __forceinline__ void get_p(const float* pre, const float* pim, int d,
                                      float& pr, float& pi) {
    float re = pre[d], im = pim[d];
    float r = sqrtf(re * re + im * im);
    float t = tanhf(r) / fmaxf(r, 1e-30f);
    pr = re * t; pi = im * t;
}

// per-chunk local scan (zero init), fused LN1+SiLU recompute, float4 over d.
// block = (chunk c, batch b); thread owns d = 4*tid .. 4*tid+3.
__global__ __launch_bounds__(256)
void scan_partial(const float* __restrict__ x, const float2* __restrict__ st,
                  const float* __restrict__ lw, const float* __restrict__ lb,
                  const float* __restrict__ pre, const float* __restrict__ pim,
                  float2* __restrict__ e) {
    const int tid = threadIdx.x;
    const int c = blockIdx.x;
    const int bb = blockIdx.y;
    const int d0 = tid * 4;
    float pr[4], pi[4];
    #pragma unroll
    for (int k = 0; k < 4; ++k) get_p(pre, pim, d0 + k, pr[k], pi[k]);
    const float4 wv = *(const float4*)(lw + d0);
    const float4 bv = *(const float4*)(lb + d0);
    const float wa[4] = {wv.x, wv.y, wv.z, wv.w};
    const float ba[4] = {bv.x, bv.y, bv.z, bv.w};
    const size_t row0 = (size_t)bb * SEQL + (size_t)c * CLEN2;
    float sr[4] = {0.f, 0.f, 0.f, 0.f}, si[4] = {0.f, 0.f, 0.f, 0.f};
    #pragma unroll
    for (int j = 0; j < CLEN2; ++j) {
        float4 v = *(const float4*)(x + (row0 + j) * DIMD + d0);
        float2 sj = st[row0 + j];
        const float xa[4] = {v.x, v.y, v.z, v.w};
        #pragma unroll
        for (int k = 0; k < 4; ++k) {
            float o = (xa[k] - sj.x) * sj.y * wa[k] + ba[k];
            float h = o / (1.f + __expf(-o));
            float nr = pr[k] * sr[k] - pi[k] * si[k] + h;
            float ni = pr[k] * si[k] + pi[k] * sr[k];
            sr[k] = nr; si[k] = ni;
        }
    }
    float2* ep = e + ((size_t)bb * CHUNKS2 + c) * DIMD + d0;
    #pragma unroll
    for (int k = 0; k < 4; ++k) ep[k] = make_float2(sr[k], si[k]);
}

// sequential combine over 128 chunks: sv[b][c][d] = state entering chunk c
__global__ __launch_bounds__(256)
void scan_combine(const float2* __restrict__ e, const float* __restrict__ pre,
                  const float* __restrict__ pim, const float* __restrict__ lre,
                  const float* __restrict__ lim, float2* __restrict__ sv) {
    const int d = blockIdx.x * 256 + threadIdx.x;
    const int bb = blockIdx.y;
    float pr, pi; get_p(pre, pim, d, pr, pi);
    float qr = pr, qi = pi;                 // p^16 via 4 squarings
    #pragma unroll
    for (int s = 0; s < 4; ++s) {
        float nr = qr * qr - qi * qi;
        float ni = 2.f * qr * qi;
        qr = nr; qi = ni;
    }
    float sr = lre[d], si = lim[d];
    for (int c = 0; c < CHUNKS2; ++c) {
        sv[((size_t)bb * CHUNKS2 + c) * DIMD + d] = make_float2(sr, si);
        float2 ec = e[((size_t)bb * CHUNKS2 + c) * DIMD + d];
        float nr = qr * sr - qi * si + ec.x;
        float ni = qr * si + qi * sr + ec.y;
        sr = nr; si = ni;
    }
}

// final scan with true incoming state; x2 = x + sc*Re(c); float4 over d.
__global__ __launch_bounds__(256)
void scan_final(const float* __restrict__ x, const float2* __restrict__ st,
                const float* __restrict__ lw, const float* __restrict__ lb,
                const float* __restrict__ pre, const float* __restrict__ pim,
                const float* __restrict__ sc, const float2* __restrict__ sv,
                float* __restrict__ x2) {
    const int tid = threadIdx.x;
    const int c = blockIdx.x;
    const int bb = blockIdx.y;
    const int d0 = tid * 4;
    float pr[4], pi[4];
    #pragma unroll
    for (int k = 0; k < 4; ++k) get_p(pre, pim, d0 + k, pr[k], pi[k]);
    const float4 wv = *(const float4*)(lw + d0);
    const float4 bv = *(const float4*)(lb + d0);
    const float4 scv = *(const float4*)(sc + d0);
    const float wa[4] = {wv.x, wv.y, wv.z, wv.w};
    const float ba[4] = {bv.x, bv.y, bv.z, bv.w};
    const float sca[4] = {scv.x, scv.y, scv.z, scv.w};
    const size_t row0 = (size_t)bb * SEQL + (size_t)c * CLEN2;
    float sr[4], si[4];
    {
        const float2* s0 = sv + ((size_t)bb * CHUNKS2 + c) * DIMD + d0;
        #pragma unroll
        for (int k = 0; k < 4; ++k) { sr[k] = s0[k].x; si[k] = s0[k].y; }
    }
    #pragma unroll
    for (int j = 0; j < CLEN2; ++j) {
        float4 v = *(const float4*)(x + (row0 + j) * DIMD + d0);
        float2 sj = st[row0 + j];
        const float xa[4] = {v.x, v.y, v.z, v.w};
        float out[4];
        #pragma unroll
        for (int k = 0; k < 4; ++k) {
            float o = (xa[k] - sj.x) * sj.y * wa[k] + ba[k];
            float h = o / (1.f + __expf(-o));
            float nr = pr[k] * sr[k] - pi[k] * si[k] + h;
            float ni = pr[k] * si[k] + pi[k] * sr[k];
            sr[k] = nr; si[k] = ni;
            out[k] = xa[k] + sca[k] * nr;
        }
        float4 ov = {out[0], out[1], out[2], out[3]};
        *(float4*)(x2 + (row0 + j) * DIMD + d0) = ov;
    }
}

// ---------------------------------------------------------------------------
// GEMM1: 32x32x16 MFMA, m97 2-barrier 128x128 tile, 32KB LDS, XCD-chunked.
//  A/B frag: row = lane&31, k = (lane>>5)*8 + e
//  C/D frag: col = lane&31, row = (reg&3) + 8*(reg>>2) + 4*(lane>>5)
// out_h = fp16(silu(C + bias)).
// ---------------------------------------------------------------------------
#define GBM 128
#define GBN 128
#define GBK 64

template<int NCOLS>
__global__ __launch_bounds__(256)
void gemm1_32(const _Float16* __restrict__ A, const _Float16* __restrict__ W,
              const float* __restrict__ bias, _Float16* __restrict__ out_h,
              int N, int K) {
    __shared__ _Float16 As[GBM * GBK];
    __shared__ _Float16 Bs[GBN * GBK];
    const int tid  = threadIdx.x;
    const int lane = tid & 63;
    const int wave = tid >> 6;
    const int wm = (wave >> 1) * 64;
    const int wn = (wave & 1) * 64;
    const int n  = blockIdx.y * gridDim.x + blockIdx.x;
    const int xc = n & 7, ii = n >> 3;
    const size_t m0 = (size_t)(xc + ((ii / NCOLS) << 3)) * GBM;
    const size_t n0 = (size_t)(ii % NCOLS) * GBN;
    const int r32 = lane & 31;
    const int kg  = lane >> 5;

    const int srow = wave * 32 + (lane >> 3);
    const int ccp  = ((lane & 7) ^ (lane >> 3)) * 8;
    const _Float16* ag = A + (m0 + srow) * (size_t)K + ccp;
    const _Float16* wg = W + (n0 + srow) * (size_t)K + ccp;
    _Float16* asl = &As[(wave * 32) * GBK];
    _Float16* bsl = &Bs[(wave * 32) * GBK];

    floatx16 acc[2][2] = {};

    for (int k0 = 0; k0 < K; k0 += GBK) {
        #pragma unroll
        for (int t = 0; t < 4; ++t) {
            load_lds16(ag + k0 + (size_t)(t * 8) * K, asl + t * 8 * GBK);
            load_lds16(wg + k0 + (size_t)(t * 8) * K, bsl + t * 8 * GBK);
        }
        __syncthreads();
        #pragma unroll
        for (int ks = 0; ks < 4; ++ks) {
            const int slot = (((ks << 1) | kg) ^ (r32 & 7)) * 8;
            half8 af0 = *(const half8*)(&As[(wm +      r32) * GBK + slot]);
            half8 af1 = *(const half8*)(&As[(wm + 32 + r32) * GBK + slot]);
            half8 bf0 = *(const half8*)(&Bs[(wn +      r32) * GBK + slot]);
            half8 bf1 = *(const half8*)(&Bs[(wn + 32 + r32) * GBK + slot]);
            acc[0][0] = __builtin_amdgcn_mfma_f32_32x32x16_f16(af0, bf0, acc[0][0], 0, 0, 0);
            acc[0][1] = __builtin_amdgcn_mfma_f32_32x32x16_f16(af0, bf1, acc[0][1], 0, 0, 0);
            acc[1][0] = __builtin_amdgcn_mfma_f32_32x32x16_f16(af1, bf0, acc[1][0], 0, 0, 0);
            acc[1][1] = __builtin_amdgcn_mfma_f32_32x32x16_f16(af1, bf1, acc[1][1], 0, 0, 0);
        }
        __syncthreads();
    }

    #pragma unroll
    for (int ib = 0; ib < 2; ++ib) {
        #pragma unroll
        for (int jb = 0; jb < 2; ++jb) {
            const size_t gn = n0 + wn + jb * 32 + r32;
            const float bb = bias[gn];
            #pragma unroll
            for (int r = 0; r < 16; ++r) {
                const size_t gm = m0 + wm + ib * 32 + (r & 3) + 8 * (r >> 2) + 4 * kg;
                float v = acc[ib][jb][r] + bb;
                float sl = v / (1.f + __expf(-v));
                out_h[gm * (size_t)N + gn] = (_Float16)sl;
            }
        }
    }
}

// ---------------------------------------------------------------------------
// GEMM2: 16x16x32 MFMA, m97 2-barrier 128x128 tile (r4 kernel, 0 conflicts),
// XCD-chunked.  out_f = C + bias + resid.
// ---------------------------------------------------------------------------
template<int NCOLS>
__global__ __launch_bounds__(256)
void gemm2_16(const _Float16* __restrict__ A, const _Float16* __restrict__ W,
              const float* __restrict__ bias, const float* __restrict__ resid,
              float* __restrict__ out_f, int N, int K) {
    __shared__ _Float16 As[GBM * GBK];
    __shared__ _Float16 Bs[GBN * GBK];
    const int tid  = threadIdx.x;
    const int lane = tid & 63;
    const int wave = tid >> 6;
    const int wm = (wave >> 1) * 64;
    const int wn = (wave & 1) * 64;
    const int n  = blockIdx.y * gridDim.x + blockIdx.x;
    const int xc = n & 7, ii = n >> 3;
    const size_t m0 = (size_t)(xc + ((ii / NCOLS) << 3)) * GBM;
    const size_t n0 = (size_t)(ii % NCOLS) * GBN;
    const int fr = lane & 15;
    const int quad = lane >> 4;

    const int srow = wave * 32 + (lane >> 3);
    const int ccp  = ((lane & 7) ^ (lane >> 3)) * 8;
    const _Float16* ag = A + (m0 + srow) * (size_t)K + ccp;
    const _Float16* wg = W + (n0 + srow) * (size_t)K + ccp;
    _Float16* asl = &As[(wave * 32) * GBK];
    _Float16* bsl = &Bs[(wave * 32) * GBK];

    floatx4 acc[4][4] = {};

    for (int k0 = 0; k0 < K; k0 += GBK) {
        #pragma unroll
        for (int t = 0; t < 4; ++t) {
            load_lds16(ag + k0 + (size_t)(t * 8) * K, asl + t * 8 * GBK);
            load_lds16(wg + k0 + (size_t)(t * 8) * K, bsl + t * 8 * GBK);
        }
        __syncthreads();
        #pragma unroll
        for (int kk = 0; kk < GBK; kk += 32) {
            half8 af[4], bf[4];
            #pragma unroll
            for (int i = 0; i < 4; ++i) {
                const int slot = (((kk >> 3) + quad) ^ (fr & 7)) * 8;
                af[i] = *(const half8*)(&As[(wm + i * 16 + fr) * GBK + slot]);
                bf[i] = *(const half8*)(&Bs[(wn + i * 16 + fr) * GBK + slot]);
            }
            #pragma unroll
            for (int i = 0; i < 4; ++i)
                #pragma unroll
                for (int j = 0; j < 4; ++j)
                    acc[i][j] = __builtin_amdgcn_mfma_f32_16x16x32_f16(
                        af[i], bf[j], acc[i][j], 0, 0, 0);
        }
        __syncthreads();
    }

    #pragma unroll
    for (int i = 0; i < 4; ++i) {
        #pragma unroll
        for (int j = 0; j < 4; ++j) {
            #pragma unroll
            for (int r = 0; r < 4; ++r) {
                const size_t gm = m0 + wm + i * 16 + quad * 4 + r;
                const size_t gn = n0 + wn + j * 16 + fr;
                float v = acc[i][j][r] + bias[gn];
                out_f[gm * (size_t)N + gn] = v + resid[gm * (size_t)N + gn];
            }
        }
    }
}

extern "C" void kernel_launch(void* const* d_in, const int* in_sizes, int n_in,
                              void* d_out, int out_size, void* d_ws, size_t ws_size,
                              hipStream_t stream) {
    const float* x    = (const float*)d_in[0];
    const float* ln1w = (const float*)d_in[1];
    const float* ln1b = (const float*)d_in[2];
    const float* ln2w = (const float*)d_in[3];
    const float* ln2b = (const float*)d_in[4];
    const float* sc   = (const float*)d_in[5];
    const float* pre  = (const float*)d_in[6];
    const float* pim  = (const float*)d_in[7];
    const float* lre  = (const float*)d_in[8];
    const float* lim  = (const float*)d_in[9];
    const float* w1   = (const float*)d_in[10];
    const float* b1   = (const float*)d_in[11];
    const float* w2   = (const float*)d_in[12];
    const float* b2   = (const float*)d_in[13];

    char* ws = (char*)d_ws;
    float2*     st  = (float2*)(ws + ST_OFF);
    float2*     e   = (float2*)(ws + E_OFF);
    float2*     sv  = (float2*)(ws + SV_OFF);
    _Float16*   h2  = (_Float16*)(ws + H2_OFF);
    _Float16*   w1h = (_Float16*)(ws + W1H_OFF);
    _Float16*   w2h = (_Float16*)(ws + W2H_OFF);
    _Float16*   y1  = (_Float16*)(ws + Y1_OFF);
    float*      x2  = (float*)d_out;
    float*      outp = (float*)d_out;

    cast_f32_f16<<<dim3(FFD * DIMD / 1024), 256, 0, stream>>>(w1, w1h);
    cast_f32_f16<<<dim3(FFD * DIMD / 1024), 256, 0, stream>>>(w2, w2h);
    ln_stats<<<dim3(MROWS), 256, 0, stream>>>(x, st);
    scan_partial<<<dim3(CHUNKS2, BATCH), 256, 0, stream>>>(
        x, st, ln1w, ln1b, pre, pim, e);
    scan_combine<<<dim3(DIMD / 256, BATCH), 256, 0, stream>>>(
        e, pre, pim, lre, lim, sv);
    scan_final<<<dim3(CHUNKS2, BATCH), 256, 0, stream>>>(
        x, st, ln1w, ln1b, pre, pim, sc, sv, x2);
    ln_kernel<<<dim3(MROWS), 256, 0, stream>>>(x2, ln2w, ln2b, h2);
    gemm1_32<32><<<dim3(FFD / GBN, MROWS / GBM), 256, 0, stream>>>(
        h2, w1h, b1, y1, FFD, DIMD);
    gemm2_16<8><<<dim3(DIMD / GBN, MROWS / GBM), 256, 0, stream>>>(
        y1, w2h, b2, x2, outp, DIMD, FFD);
}

// Round 7
// 353.742 us; speedup vs baseline: 1.0232x; 1.0232x over previous
//
#include <hip/hip_runtime.h>
#include <cmath>

// ---------------------------------------------------------------------------
// SConvNetBlock: LN1 -> SiLU -> complex-decay scan -> *sc_lin -> +res
//                -> LN2 -> FFN(GEMM+SiLU+GEMM) -> +res
// Round-7: measured-best component assembly.
//  * NG suite: r3/r5 proven column-parallel scans, CHUNKS=32 (combine is a
//    serial per-chunk recurrence -> keep iteration count LOW; CHUNKS=128
//    cost ~36us in r4/r6), ln_stats + inline LN1+SiLU recompute, ln_kernel.
//  * GEMM1 (8192x4096x1024): 32x32x16 MFMA 128x128 2-barrier (102us best).
//  * GEMM2 (8192x1024x4096): 16x16x32 MFMA 128x128 2-barrier (0 conflicts;
//    32x32 variant costs ~+30us here -- conflict penalty x64 K-tiles).
// ---------------------------------------------------------------------------

#define DIMD 1024
#define FFD  4096
#define BATCH 4
#define SEQL 2048
#define MROWS (BATCH*SEQL)      // 8192
#define EPSF 1e-5f
#define CHUNKS 32
#define CLEN (SEQL/CHUNKS)      // 64

typedef __attribute__((ext_vector_type(8)))  _Float16 half8;
typedef __attribute__((ext_vector_type(4)))  _Float16 half4;
typedef __attribute__((ext_vector_type(4)))  float    floatx4;
typedef __attribute__((ext_vector_type(16))) float    floatx16;

// ---- workspace layout (bytes) ----
#define ST_OFF   0u                       // st  float2 [8192]        64 KB
#define E_OFF    33554432u                // e   float2 [4][32][1024]  1 MB
#define SIN_OFF  34603008u                // sv  float2 [4][32][1024]  1 MB
#define H2_OFF   35651584u                // h2  fp16 [8192][1024]    16 MB
#define W1H_OFF  52428800u                // w1h fp16 [4096][1024]     8 MB
#define W2H_OFF  60817408u                // w2h fp16 [1024][4096]     8 MB
#define Y1_OFF   69206016u                // y1  fp16 [8192][4096]    64 MB

__device__ __forceinline__ void load_lds16(const _Float16* g, _Float16* l) {
    __builtin_amdgcn_global_load_lds(
        (const __attribute__((address_space(1))) unsigned int*)g,
        (__attribute__((address_space(3))) unsigned int*)l,
        16, 0, 0);
}

__global__ __launch_bounds__(256)
void cast_f32_f16(const float* __restrict__ src, _Float16* __restrict__ dst) {
    int i = (blockIdx.x * 256 + threadIdx.x) * 4;
    float4 v = *(const float4*)(src + i);
    half4 o;
    o.x = (_Float16)v.x; o.y = (_Float16)v.y; o.z = (_Float16)v.z; o.w = (_Float16)v.w;
    *(half4*)(dst + i) = o;
}

// per-row LN statistics: st[row] = (mu, rsqrt(var+eps))
__global__ __launch_bounds__(256)
void ln_stats(const float* __restrict__ x, float2* __restrict__ st) {
    const size_t row = blockIdx.x;
    const int tid = threadIdx.x;
    float4 v = *(const float4*)(x + row * DIMD + tid * 4);
    float s = (v.x + v.y) + (v.z + v.w);
    float q = (v.x * v.x + v.y * v.y) + (v.z * v.z + v.w * v.w);
    #pragma unroll
    for (int off = 32; off; off >>= 1) {
        s += __shfl_down(s, off, 64);
        q += __shfl_down(q, off, 64);
    }
    __shared__ float red[8];
    if (!(tid & 63)) { red[tid >> 6] = s; red[4 + (tid >> 6)] = q; }
    __syncthreads();
    if (tid == 0) {
        s = (red[0] + red[1]) + (red[2] + red[3]);
        q = (red[4] + red[5]) + (red[6] + red[7]);
        const float mu = s * (1.f / DIMD);
        const float rs = rsqrtf(q * (1.f / DIMD) - mu * mu + EPSF);
        st[row] = make_float2(mu, rs);
    }
}

// LN2: out fp16 = LN(x)
__global__ __launch_bounds__(256)
void ln_kernel(const float* __restrict__ x, const float* __restrict__ w,
               const float* __restrict__ b, _Float16* __restrict__ oh) {
    const size_t row = blockIdx.x;
    const int tid = threadIdx.x;
    float4 v = *(const float4*)(x + row * DIMD + tid * 4);
    float s = (v.x + v.y) + (v.z + v.w);
    float q = (v.x * v.x + v.y * v.y) + (v.z * v.z + v.w * v.w);
    #pragma unroll
    for (int off = 32; off; off >>= 1) {
        s += __shfl_down(s, off, 64);
        q += __shfl_down(q, off, 64);
    }
    __shared__ float red[8];
    if (!(tid & 63)) { red[tid >> 6] = s; red[4 + (tid >> 6)] = q; }
    __syncthreads();
    s = (red[0] + red[1]) + (red[2] + red[3]);
    q = (red[4] + red[5]) + (red[6] + red[7]);
    const float mu = s * (1.f / DIMD);
    const float rs = rsqrtf(q * (1.f / DIMD) - mu * mu + EPSF);
    float4 wv = *(const float4*)(w + tid * 4);
    float4 bv = *(const float4*)(b + tid * 4);
    half4 hv;
    hv.x = (_Float16)((v.x - mu) * rs * wv.x + bv.x);
    hv.y = (_Float16)((v.y - mu) * rs * wv.y + bv.y);
    hv.z = (_Float16)((v.z - mu) * rs * wv.z + bv.z);
    hv.w = (_Float16)((v.w - mu) * rs * wv.w + bv.w);
    *(half4*)(oh + row * DIMD + tid * 4) = hv;
}

__device__ __forceinline__ void get_p(const float* pre, const float* pim, int d,
                                      float& pr, float& pi) {
    float re = pre[d], im = pim[d];
    float r = sqrtf(re * re + im * im);
    float t = tanhf(r) / fmaxf(r, 1e-30f);
    pr = re * t; pi = im * t;
}

__device__ __forceinline__ float ln_silu(float xv, float2 st, float wd, float bd) {
    float o = (xv - st.x) * st.y * wd + bd;
    return o / (1.f + __expf(-o));
}

// per-chunk local scan (zero init) with fused LN1+SiLU recompute from x
__global__ __launch_bounds__(256)
void scan_partial(const float* __restrict__ x, const float2* __restrict__ st,
                  const float* __restrict__ lw, const float* __restrict__ lb,
                  const float* __restrict__ pre, const float* __restrict__ pim,
                  float2* __restrict__ e) {
    const int d = blockIdx.x * 256 + threadIdx.x;
    const int c = blockIdx.y;
    const int bb = blockIdx.z;
    float pr, pi; get_p(pre, pim, d, pr, pi);
    const float wd = lw[d], bd = lb[d];
    float sr = 0.f, si = 0.f;
    const size_t row0 = (size_t)bb * SEQL + (size_t)c * CLEN;
    #pragma unroll 4
    for (int j = 0; j < CLEN; ++j) {
        float xv = x[(row0 + j) * DIMD + d];
        float2 sj = st[row0 + j];
        float hv = ln_silu(xv, sj, wd, bd);
        float nr = pr * sr - pi * si + hv;
        float ni = pr * si + pi * sr;
        sr = nr; si = ni;
    }
    e[((size_t)bb * CHUNKS + c) * DIMD + d] = make_float2(sr, si);
}

// sequential combine over chunks: sv[b][c][d] = state entering chunk c
__global__ __launch_bounds__(256)
void scan_combine(const float2* __restrict__ e, const float* __restrict__ pre,
                  const float* __restrict__ pim, const float* __restrict__ lre,
                  const float* __restrict__ lim, float2* __restrict__ sv) {
    const int d = blockIdx.x * 256 + threadIdx.x;
    const int bb = blockIdx.y;
    float pr, pi; get_p(pre, pim, d, pr, pi);
    float qr = pr, qi = pi;                 // p^64 via 6 squarings
    #pragma unroll
    for (int s = 0; s < 6; ++s) {
        float nr = qr * qr - qi * qi;
        float ni = 2.f * qr * qi;
        qr = nr; qi = ni;
    }
    float sr = lre[d], si = lim[d];
    for (int c = 0; c < CHUNKS; ++c) {
        sv[((size_t)bb * CHUNKS + c) * DIMD + d] = make_float2(sr, si);
        float2 ec = e[((size_t)bb * CHUNKS + c) * DIMD + d];
        float nr = qr * sr - qi * si + ec.x;
        float ni = qr * si + qi * sr + ec.y;
        sr = nr; si = ni;
    }
}

// final scan with true incoming state; x2 = x + sc*Re(c); x read ONCE
__global__ __launch_bounds__(256)
void scan_final(const float* __restrict__ x, const float2* __restrict__ st,
                const float* __restrict__ lw, const float* __restrict__ lb,
                const float* __restrict__ pre, const float* __restrict__ pim,
                const float* __restrict__ sc, const float2* __restrict__ sv,
                float* __restrict__ x2) {
    const int d = blockIdx.x * 256 + threadIdx.x;
    const int c = blockIdx.y;
    const int bb = blockIdx.z;
    float pr, pi; get_p(pre, pim, d, pr, pi);
    const float wd = lw[d], bd = lb[d];
    float2 s0 = sv[((size_t)bb * CHUNKS + c) * DIMD + d];
    float sr = s0.x, si = s0.y;
    const float scd = sc[d];
    const size_t row0 = (size_t)bb * SEQL + (size_t)c * CLEN;
    #pragma unroll 4
    for (int j = 0; j < CLEN; ++j) {
        float xv = x[(row0 + j) * DIMD + d];
        float2 sj = st[row0 + j];
        float hv = ln_silu(xv, sj, wd, bd);
        float nr = pr * sr - pi * si + hv;
        float ni = pr * si + pi * sr;
        sr = nr; si = ni;
        x2[(row0 + j) * DIMD + d] = xv + scd * sr;
    }
}

// ---------------------------------------------------------------------------
// GEMM1: 32x32x16 MFMA, m97 2-barrier 128x128 tile, 32KB LDS, XCD-chunked.
//  A/B frag: row = lane&31, k = (lane>>5)*8 + e
//  C/D frag: col = lane&31, row = (reg&3) + 8*(reg>>2) + 4*(lane>>5)
// out_h = fp16(silu(C + bias)).
// ---------------------------------------------------------------------------
#define GBM 128
#define GBN 128
#define GBK 64

template<int NCOLS>
__global__ __launch_bounds__(256)
void gemm1_32(const _Float16* __restrict__ A, const _Float16* __restrict__ W,
              const float* __restrict__ bias, _Float16* __restrict__ out_h,
              int N, int K) {
    __shared__ _Float16 As[GBM * GBK];
    __shared__ _Float16 Bs[GBN * GBK];
    const int tid  = threadIdx.x;
    const int lane = tid & 63;
    const int wave = tid >> 6;
    const int wm = (wave >> 1) * 64;
    const int wn = (wave & 1) * 64;
    const int n  = blockIdx.y * gridDim.x + blockIdx.x;
    const int xc = n & 7, ii = n >> 3;
    const size_t m0 = (size_t)(xc + ((ii / NCOLS) << 3)) * GBM;
    const size_t n0 = (size_t)(ii % NCOLS) * GBN;
    const int r32 = lane & 31;
    const int kg  = lane >> 5;

    const int srow = wave * 32 + (lane >> 3);
    const int ccp  = ((lane & 7) ^ (lane >> 3)) * 8;
    const _Float16* ag = A + (m0 + srow) * (size_t)K + ccp;
    const _Float16* wg = W + (n0 + srow) * (size_t)K + ccp;
    _Float16* asl = &As[(wave * 32) * GBK];
    _Float16* bsl = &Bs[(wave * 32) * GBK];

    floatx16 acc[2][2] = {};

    for (int k0 = 0; k0 < K; k0 += GBK) {
        #pragma unroll
        for (int t = 0; t < 4; ++t) {
            load_lds16(ag + k0 + (size_t)(t * 8) * K, asl + t * 8 * GBK);
            load_lds16(wg + k0 + (size_t)(t * 8) * K, bsl + t * 8 * GBK);
        }
        __syncthreads();
        #pragma unroll
        for (int ks = 0; ks < 4; ++ks) {
            const int slot = (((ks << 1) | kg) ^ (r32 & 7)) * 8;
            half8 af0 = *(const half8*)(&As[(wm +      r32) * GBK + slot]);
            half8 af1 = *(const half8*)(&As[(wm + 32 + r32) * GBK + slot]);
            half8 bf0 = *(const half8*)(&Bs[(wn +      r32) * GBK + slot]);
            half8 bf1 = *(const half8*)(&Bs[(wn + 32 + r32) * GBK + slot]);
            acc[0][0] = __builtin_amdgcn_mfma_f32_32x32x16_f16(af0, bf0, acc[0][0], 0, 0, 0);
            acc[0][1] = __builtin_amdgcn_mfma_f32_32x32x16_f16(af0, bf1, acc[0][1], 0, 0, 0);
            acc[1][0] = __builtin_amdgcn_mfma_f32_32x32x16_f16(af1, bf0, acc[1][0], 0, 0, 0);
            acc[1][1] = __builtin_amdgcn_mfma_f32_32x32x16_f16(af1, bf1, acc[1][1], 0, 0, 0);
        }
        __syncthreads();
    }

    #pragma unroll
    for (int ib = 0; ib < 2; ++ib) {
        #pragma unroll
        for (int jb = 0; jb < 2; ++jb) {
            const size_t gn = n0 + wn + jb * 32 + r32;
            const float bb = bias[gn];
            #pragma unroll
            for (int r = 0; r < 16; ++r) {
                const size_t gm = m0 + wm + ib * 32 + (r & 3) + 8 * (r >> 2) + 4 * kg;
                float v = acc[ib][jb][r] + bb;
                float sl = v / (1.f + __expf(-v));
                out_h[gm * (size_t)N + gn] = (_Float16)sl;
            }
        }
    }
}

// ---------------------------------------------------------------------------
// GEMM2: 16x16x32 MFMA, m97 2-barrier 128x128 tile (0 conflicts),
// XCD-chunked.  out_f = C + bias + resid.
// ---------------------------------------------------------------------------
template<int NCOLS>
__global__ __launch_bounds__(256)
void gemm2_16(const _Float16* __restrict__ A, const _Float16* __restrict__ W,
              const float* __restrict__ bias, const float* __restrict__ resid,
              float* __restrict__ out_f, int N, int K) {
    __shared__ _Float16 As[GBM * GBK];
    __shared__ _Float16 Bs[GBN * GBK];
    const int tid  = threadIdx.x;
    const int lane = tid & 63;
    const int wave = tid >> 6;
    const int wm = (wave >> 1) * 64;
    const int wn = (wave & 1) * 64;
    const int n  = blockIdx.y * gridDim.x + blockIdx.x;
    const int xc = n & 7, ii = n >> 3;
    const size_t m0 = (size_t)(xc + ((ii / NCOLS) << 3)) * GBM;
    const size_t n0 = (size_t)(ii % NCOLS) * GBN;
    const int fr = lane & 15;
    const int quad = lane >> 4;

    const int srow = wave * 32 + (lane >> 3);
    const int ccp  = ((lane & 7) ^ (lane >> 3)) * 8;
    const _Float16* ag = A + (m0 + srow) * (size_t)K + ccp;
    const _Float16* wg = W + (n0 + srow) * (size_t)K + ccp;
    _Float16* asl = &As[(wave * 32) * GBK];
    _Float16* bsl = &Bs[(wave * 32) * GBK];

    floatx4 acc[4][4] = {};

    for (int k0 = 0; k0 < K; k0 += GBK) {
        #pragma unroll
        for (int t = 0; t < 4; ++t) {
            load_lds16(ag + k0 + (size_t)(t * 8) * K, asl + t * 8 * GBK);
            load_lds16(wg + k0 + (size_t)(t * 8) * K, bsl + t * 8 * GBK);
        }
        __syncthreads();
        #pragma unroll
        for (int kk = 0; kk < GBK; kk += 32) {
            half8 af[4], bf[4];
            #pragma unroll
            for (int i = 0; i < 4; ++i) {
                const int slot = (((kk >> 3) + quad) ^ (fr & 7)) * 8;
                af[i] = *(const half8*)(&As[(wm + i * 16 + fr) * GBK + slot]);
                bf[i] = *(const half8*)(&Bs[(wn + i * 16 + fr) * GBK + slot]);
            }
            #pragma unroll
            for (int i = 0; i < 4; ++i)
                #pragma unroll
                for (int j = 0; j < 4; ++j)
                    acc[i][j] = __builtin_amdgcn_mfma_f32_16x16x32_f16(
                        af[i], bf[j], acc[i][j], 0, 0, 0);
        }
        __syncthreads();
    }

    #pragma unroll
    for (int i = 0; i < 4; ++i) {
        #pragma unroll
        for (int j = 0; j < 4; ++j) {
            #pragma unroll
            for (int r = 0; r < 4; ++r) {
                const size_t gm = m0 + wm + i * 16 + quad * 4 + r;
                const size_t gn = n0 + wn + j * 16 + fr;
                float v = acc[i][j][r] + bias[gn];
                out_f[gm * (size_t)N + gn] = v + resid[gm * (size_t)N + gn];
            }
        }
    }
}

extern "C" void kernel_launch(void* const* d_in, const int* in_sizes, int n_in,
                              void* d_out, int out_size, void* d_ws, size_t ws_size,
                              hipStream_t stream) {
    const float* x    = (const float*)d_in[0];
    const float* ln1w = (const float*)d_in[1];
    const float* ln1b = (const float*)d_in[2];
    const float* ln2w = (const float*)d_in[3];
    const float* ln2b = (const float*)d_in[4];
    const float* sc   = (const float*)d_in[5];
    const float* pre  = (const float*)d_in[6];
    const float* pim  = (const float*)d_in[7];
    const float* lre  = (const float*)d_in[8];
    const float* lim  = (const float*)d_in[9];
    const float* w1   = (const float*)d_in[10];
    const float* b1   = (const float*)d_in[11];
    const float* w2   = (const float*)d_in[12];
    const float* b2   = (const float*)d_in[13];

    char* ws = (char*)d_ws;
    float2*     st  = (float2*)(ws + ST_OFF);
    float2*     e   = (float2*)(ws + E_OFF);
    float2*     sv  = (float2*)(ws + SIN_OFF);
    _Float16*   h2  = (_Float16*)(ws + H2_OFF);
    _Float16*   w1h = (_Float16*)(ws + W1H_OFF);
    _Float16*   w2h = (_Float16*)(ws + W2H_OFF);
    _Float16*   y1  = (_Float16*)(ws + Y1_OFF);
    float*      x2  = (float*)d_out;
    float*      outp = (float*)d_out;

    cast_f32_f16<<<dim3(FFD * DIMD / 1024), 256, 0, stream>>>(w1, w1h);
    cast_f32_f16<<<dim3(FFD * DIMD / 1024), 256, 0, stream>>>(w2, w2h);
    ln_stats<<<dim3(MROWS), 256, 0, stream>>>(x, st);
    scan_partial<<<dim3(DIMD / 256, CHUNKS, BATCH), 256, 0, stream>>>(
        x, st, ln1w, ln1b, pre, pim, e);
    scan_combine<<<dim3(DIMD / 256, BATCH), 256, 0, stream>>>(
        e, pre, pim, lre, lim, sv);
    scan_final<<<dim3(DIMD / 256, CHUNKS, BATCH), 256, 0, stream>>>(
        x, st, ln1w, ln1b, pre, pim, sc, sv, x2);
    ln_kernel<<<dim3(MROWS), 256, 0, stream>>>(x2, ln2w, ln2b, h2);
    gemm1_32<32><<<dim3(FFD / GBN, MROWS / GBM), 256, 0, stream>>>(
        h2, w1h, b1, y1, FFD, DIMD);
    gemm2_16<8><<<dim3(DIMD / GBN, MROWS / GBM), 256, 0, stream>>>(
        y1, w2h, b2, x2, outp, DIMD, FFD);
}

// Round 9
// 345.132 us; speedup vs baseline: 1.0487x; 1.0249x over previous
//
#include <hip/hip_runtime.h>
#include <cmath>

// ---------------------------------------------------------------------------
// SConvNetBlock: LN1 -> SiLU -> complex-decay scan -> *sc_lin -> +res
//                -> LN2 -> FFN(GEMM+SiLU+GEMM) -> +res
// Round-9: r8 with prep grid FIXED (cast needs FFD*DIMD/1024 = 4096 blocks
// per weight; r8 launched 1024 -> 3/4 of w1h/w2h stale -> absmax 16.45).
//  * prep = cast(w1) + cast(w2) + ln_stats fused by grid partition (1 launch).
//  * scan_combine DELETED: scan_final folds incoming chunk state inline
//    from e (1MB, L2-resident; identical arithmetic order as before).
//  * 6 launches total: prep, scan_partial, scan_final, ln_kernel,
//    gemm1_32 (32x32x16), gemm2_16 (16x16x32) -- best measured cell.
// ---------------------------------------------------------------------------

#define DIMD 1024
#define FFD  4096
#define BATCH 4
#define SEQL 2048
#define MROWS (BATCH*SEQL)      // 8192
#define EPSF 1e-5f
#define CHUNKS 32
#define CLEN (SEQL/CHUNKS)      // 64
#define CAST_BLKS (FFD*DIMD/1024)   // 4096 blocks per weight cast

typedef __attribute__((ext_vector_type(8)))  _Float16 half8;
typedef __attribute__((ext_vector_type(4)))  _Float16 half4;
typedef __attribute__((ext_vector_type(4)))  float    floatx4;
typedef __attribute__((ext_vector_type(16))) float    floatx16;

// ---- workspace layout (bytes) ----
#define ST_OFF   0u                       // st  float2 [8192]        64 KB
#define E_OFF    33554432u                // e   float2 [4][32][1024]  1 MB
#define H2_OFF   35651584u                // h2  fp16 [8192][1024]    16 MB
#define W1H_OFF  52428800u                // w1h fp16 [4096][1024]     8 MB
#define W2H_OFF  60817408u                // w2h fp16 [1024][4096]     8 MB
#define Y1_OFF   69206016u                // y1  fp16 [8192][4096]    64 MB

__device__ __forceinline__ void load_lds16(const _Float16* g, _Float16* l) {
    __builtin_amdgcn_global_load_lds(
        (const __attribute__((address_space(1))) unsigned int*)g,
        (__attribute__((address_space(3))) unsigned int*)l,
        16, 0, 0);
}

// ---------------------------------------------------------------------------
// prep: blocks [0,8192) = ln_stats rows; [8192,12288) = cast w1;
//       [12288,16384) = cast w2.   (4096 cast blocks per weight.)
// ---------------------------------------------------------------------------
__global__ __launch_bounds__(256)
void prep(const float* __restrict__ x, float2* __restrict__ st,
          const float* __restrict__ w1, _Float16* __restrict__ w1h,
          const float* __restrict__ w2, _Float16* __restrict__ w2h) {
    const int bid = blockIdx.x;
    const int tid = threadIdx.x;
    if (bid < MROWS) {
        const size_t row = bid;
        float4 v = *(const float4*)(x + row * DIMD + tid * 4);
        float s = (v.x + v.y) + (v.z + v.w);
        float q = (v.x * v.x + v.y * v.y) + (v.z * v.z + v.w * v.w);
        #pragma unroll
        for (int off = 32; off; off >>= 1) {
            s += __shfl_down(s, off, 64);
            q += __shfl_down(q, off, 64);
        }
        __shared__ float red[8];
        if (!(tid & 63)) { red[tid >> 6] = s; red[4 + (tid >> 6)] = q; }
        __syncthreads();
        if (tid == 0) {
            s = (red[0] + red[1]) + (red[2] + red[3]);
            q = (red[4] + red[5]) + (red[6] + red[7]);
            const float mu = s * (1.f / DIMD);
            const float rs = rsqrtf(q * (1.f / DIMD) - mu * mu + EPSF);
            st[row] = make_float2(mu, rs);
        }
    } else {
        int b = bid - MROWS;
        const float* src;
        _Float16* dst;
        if (b < CAST_BLKS) { src = w1; dst = w1h; }
        else { b -= CAST_BLKS; src = w2; dst = w2h; }
        int i = (b * 256 + tid) * 4;
        float4 v = *(const float4*)(src + i);
        half4 o;
        o.x = (_Float16)v.x; o.y = (_Float16)v.y;
        o.z = (_Float16)v.z; o.w = (_Float16)v.w;
        *(half4*)(dst + i) = o;
    }
}

// LN2: out fp16 = LN(x)
__global__ __launch_bounds__(256)
void ln_kernel(const float* __restrict__ x, const float* __restrict__ w,
               const float* __restrict__ b, _Float16* __restrict__ oh) {
    const size_t row = blockIdx.x;
    const int tid = threadIdx.x;
    float4 v = *(const float4*)(x + row * DIMD + tid * 4);
    float s = (v.x + v.y) + (v.z + v.w);
    float q = (v.x * v.x + v.y * v.y) + (v.z * v.z + v.w * v.w);
    #pragma unroll
    for (int off = 32; off; off >>= 1) {
        s += __shfl_down(s, off, 64);
        q += __shfl_down(q, off, 64);
    }
    __shared__ float red[8];
    if (!(tid & 63)) { red[tid >> 6] = s; red[4 + (tid >> 6)] = q; }
    __syncthreads();
    s = (red[0] + red[1]) + (red[2] + red[3]);
    q = (red[4] + red[5]) + (red[6] + red[7]);
    const float mu = s * (1.f / DIMD);
    const float rs = rsqrtf(q * (1.f / DIMD) - mu * mu + EPSF);
    float4 wv = *(const float4*)(w + tid * 4);
    float4 bv = *(const float4*)(b + tid * 4);
    half4 hv;
    hv.x = (_Float16)((v.x - mu) * rs * wv.x + bv.x);
    hv.y = (_Float16)((v.y - mu) * rs * wv.y + bv.y);
    hv.z = (_Float16)((v.z - mu) * rs * wv.z + bv.z);
    hv.w = (_Float16)((v.w - mu) * rs * wv.w + bv.w);
    *(half4*)(oh + row * DIMD + tid * 4) = hv;
}

__device__ __forceinline__ void get_p(const float* pre, const float* pim, int d,
                                      float& pr, float& pi) {
    float re = pre[d], im = pim[d];
    float r = sqrtf(re * re + im * im);
    float t = tanhf(r) / fmaxf(r, 1e-30f);
    pr = re * t; pi = im * t;
}

__device__ __forceinline__ float ln_silu(float xv, float2 st, float wd, float bd) {
    float o = (xv - st.x) * st.y * wd + bd;
    return o / (1.f + __expf(-o));
}

// per-chunk local scan (zero init) with fused LN1+SiLU recompute from x
__global__ __launch_bounds__(256)
void scan_partial(const float* __restrict__ x, const float2* __restrict__ st,
                  const float* __restrict__ lw, const float* __restrict__ lb,
                  const float* __restrict__ pre, const float* __restrict__ pim,
                  float2* __restrict__ e) {
    const int d = blockIdx.x * 256 + threadIdx.x;
    const int c = blockIdx.y;
    const int bb = blockIdx.z;
    float pr, pi; get_p(pre, pim, d, pr, pi);
    const float wd = lw[d], bd = lb[d];
    float sr = 0.f, si = 0.f;
    const size_t row0 = (size_t)bb * SEQL + (size_t)c * CLEN;
    #pragma unroll 4
    for (int j = 0; j < CLEN; ++j) {
        float xv = x[(row0 + j) * DIMD + d];
        float2 sj = st[row0 + j];
        float hv = ln_silu(xv, sj, wd, bd);
        float nr = pr * sr - pi * si + hv;
        float ni = pr * si + pi * sr;
        sr = nr; si = ni;
    }
    e[((size_t)bb * CHUNKS + c) * DIMD + d] = make_float2(sr, si);
}

// final scan; incoming state folded INLINE from e (combine kernel deleted).
// x2 = x + sc*Re(c); x read once.
__global__ __launch_bounds__(256)
void scan_final(const float* __restrict__ x, const float2* __restrict__ st,
                const float* __restrict__ lw, const float* __restrict__ lb,
                const float* __restrict__ pre, const float* __restrict__ pim,
                const float* __restrict__ sc, const float* __restrict__ lre,
                const float* __restrict__ lim, const float2* __restrict__ e,
                float* __restrict__ x2) {
    const int d = blockIdx.x * 256 + threadIdx.x;
    const int c = blockIdx.y;
    const int bb = blockIdx.z;
    float pr, pi; get_p(pre, pim, d, pr, pi);
    const float wd = lw[d], bd = lb[d];
    // p^64 via 6 squarings
    float qr = pr, qi = pi;
    #pragma unroll
    for (int s = 0; s < 6; ++s) {
        float nr = qr * qr - qi * qi;
        float ni = 2.f * qr * qi;
        qr = nr; qi = ni;
    }
    // fold incoming state over chunks [0, c)  (same order as old combine)
    float sr = lre[d], si = lim[d];
    const float2* ep = e + (size_t)bb * CHUNKS * DIMD + d;
    for (int cc = 0; cc < c; ++cc) {
        float2 ec = ep[(size_t)cc * DIMD];
        float nr = qr * sr - qi * si + ec.x;
        float ni = qr * si + qi * sr + ec.y;
        sr = nr; si = ni;
    }
    const float scd = sc[d];
    const size_t row0 = (size_t)bb * SEQL + (size_t)c * CLEN;
    #pragma unroll 4
    for (int j = 0; j < CLEN; ++j) {
        float xv = x[(row0 + j) * DIMD + d];
        float2 sj = st[row0 + j];
        float hv = ln_silu(xv, sj, wd, bd);
        float nr = pr * sr - pi * si + hv;
        float ni = pr * si + pi * sr;
        sr = nr; si = ni;
        x2[(row0 + j) * DIMD + d] = xv + scd * sr;
    }
}

// ---------------------------------------------------------------------------
// GEMM1: 32x32x16 MFMA, m97 2-barrier 128x128 tile, 32KB LDS, XCD-chunked.
//  A/B frag: row = lane&31, k = (lane>>5)*8 + e
//  C/D frag: col = lane&31, row = (reg&3) + 8*(reg>>2) + 4*(lane>>5)
// out_h = fp16(silu(C + bias)).
// ---------------------------------------------------------------------------
#define GBM 128
#define GBN 128
#define GBK 64

template<int NCOLS>
__global__ __launch_bounds__(256)
void gemm1_32(const _Float16* __restrict__ A, const _Float16* __restrict__ W,
              const float* __restrict__ bias, _Float16* __restrict__ out_h,
              int N, int K) {
    __shared__ _Float16 As[GBM * GBK];
    __shared__ _Float16 Bs[GBN * GBK];
    const int tid  = threadIdx.x;
    const int lane = tid & 63;
    const int wave = tid >> 6;
    const int wm = (wave >> 1) * 64;
    const int wn = (wave & 1) * 64;
    const int n  = blockIdx.y * gridDim.x + blockIdx.x;
    const int xc = n & 7, ii = n >> 3;
    const size_t m0 = (size_t)(xc + ((ii / NCOLS) << 3)) * GBM;
    const size_t n0 = (size_t)(ii % NCOLS) * GBN;
    const int r32 = lane & 31;
    const int kg  = lane >> 5;

    const int srow = wave * 32 + (lane >> 3);
    const int ccp  = ((lane & 7) ^ (lane >> 3)) * 8;
    const _Float16* ag = A + (m0 + srow) * (size_t)K + ccp;
    const _Float16* wg = W + (n0 + srow) * (size_t)K + ccp;
    _Float16* asl = &As[(wave * 32) * GBK];
    _Float16* bsl = &Bs[(wave * 32) * GBK];

    floatx16 acc[2][2] = {};

    for (int k0 = 0; k0 < K; k0 += GBK) {
        #pragma unroll
        for (int t = 0; t < 4; ++t) {
            load_lds16(ag + k0 + (size_t)(t * 8) * K, asl + t * 8 * GBK);
            load_lds16(wg + k0 + (size_t)(t * 8) * K, bsl + t * 8 * GBK);
        }
        __syncthreads();
        #pragma unroll
        for (int ks = 0; ks < 4; ++ks) {
            const int slot = (((ks << 1) | kg) ^ (r32 & 7)) * 8;
            half8 af0 = *(const half8*)(&As[(wm +      r32) * GBK + slot]);
            half8 af1 = *(const half8*)(&As[(wm + 32 + r32) * GBK + slot]);
            half8 bf0 = *(const half8*)(&Bs[(wn +      r32) * GBK + slot]);
            half8 bf1 = *(const half8*)(&Bs[(wn + 32 + r32) * GBK + slot]);
            acc[0][0] = __builtin_amdgcn_mfma_f32_32x32x16_f16(af0, bf0, acc[0][0], 0, 0, 0);
            acc[0][1] = __builtin_amdgcn_mfma_f32_32x32x16_f16(af0, bf1, acc[0][1], 0, 0, 0);
            acc[1][0] = __builtin_amdgcn_mfma_f32_32x32x16_f16(af1, bf0, acc[1][0], 0, 0, 0);
            acc[1][1] = __builtin_amdgcn_mfma_f32_32x32x16_f16(af1, bf1, acc[1][1], 0, 0, 0);
        }
        __syncthreads();
    }

    #pragma unroll
    for (int ib = 0; ib < 2; ++ib) {
        #pragma unroll
        for (int jb = 0; jb < 2; ++jb) {
            const size_t gn = n0 + wn + jb * 32 + r32;
            const float bb = bias[gn];
            #pragma unroll
            for (int r = 0; r < 16; ++r) {
                const size_t gm = m0 + wm + ib * 32 + (r & 3) + 8 * (r >> 2) + 4 * kg;
                float v = acc[ib][jb][r] + bb;
                float sl = v / (1.f + __expf(-v));
                out_h[gm * (size_t)N + gn] = (_Float16)sl;
            }
        }
    }
}

// ---------------------------------------------------------------------------
// GEMM2: 16x16x32 MFMA, m97 2-barrier 128x128 tile (0 conflicts),
// XCD-chunked.  out_f = C + bias + resid.
// ---------------------------------------------------------------------------
template<int NCOLS>
__global__ __launch_bounds__(256)
void gemm2_16(const _Float16* __restrict__ A, const _Float16* __restrict__ W,
              const float* __restrict__ bias, const float* __restrict__ resid,
              float* __restrict__ out_f, int N, int K) {
    __shared__ _Float16 As[GBM * GBK];
    __shared__ _Float16 Bs[GBN * GBK];
    const int tid  = threadIdx.x;
    const int lane = tid & 63;
    const int wave = tid >> 6;
    const int wm = (wave >> 1) * 64;
    const int wn = (wave & 1) * 64;
    const int n  = blockIdx.y * gridDim.x + blockIdx.x;
    const int xc = n & 7, ii = n >> 3;
    const size_t m0 = (size_t)(xc + ((ii / NCOLS) << 3)) * GBM;
    const size_t n0 = (size_t)(ii % NCOLS) * GBN;
    const int fr = lane & 15;
    const int quad = lane >> 4;

    const int srow = wave * 32 + (lane >> 3);
    const int ccp  = ((lane & 7) ^ (lane >> 3)) * 8;
    const _Float16* ag = A + (m0 + srow) * (size_t)K + ccp;
    const _Float16* wg = W + (n0 + srow) * (size_t)K + ccp;
    _Float16* asl = &As[(wave * 32) * GBK];
    _Float16* bsl = &Bs[(wave * 32) * GBK];

    floatx4 acc[4][4] = {};

    for (int k0 = 0; k0 < K; k0 += GBK) {
        #pragma unroll
        for (int t = 0; t < 4; ++t) {
            load_lds16(ag + k0 + (size_t)(t * 8) * K, asl + t * 8 * GBK);
            load_lds16(wg + k0 + (size_t)(t * 8) * K, bsl + t * 8 * GBK);
        }
        __syncthreads();
        #pragma unroll
        for (int kk = 0; kk < GBK; kk += 32) {
            half8 af[4], bf[4];
            #pragma unroll
            for (int i = 0; i < 4; ++i) {
                const int slot = (((kk >> 3) + quad) ^ (fr & 7)) * 8;
                af[i] = *(const half8*)(&As[(wm + i * 16 + fr) * GBK + slot]);
                bf[i] = *(const half8*)(&Bs[(wn + i * 16 + fr) * GBK + slot]);
            }
            #pragma unroll
            for (int i = 0; i < 4; ++i)
                #pragma unroll
                for (int j = 0; j < 4; ++j)
                    acc[i][j] = __builtin_amdgcn_mfma_f32_16x16x32_f16(
                        af[i], bf[j], acc[i][j], 0, 0, 0);
        }
        __syncthreads();
    }

    #pragma unroll
    for (int i = 0; i < 4; ++i) {
        #pragma unroll
        for (int j = 0; j < 4; ++j) {
            #pragma unroll
            for (int r = 0; r < 4; ++r) {
                const size_t gm = m0 + wm + i * 16 + quad * 4 + r;
                const size_t gn = n0 + wn + j * 16 + fr;
                float v = acc[i][j][r] + bias[gn];
                out_f[gm * (size_t)N + gn] = v + resid[gm * (size_t)N + gn];
            }
        }
    }
}

extern "C" void kernel_launch(void* const* d_in, const int* in_sizes, int n_in,
                              void* d_out, int out_size, void* d_ws, size_t ws_size,
                              hipStream_t stream) {
    const float* x    = (const float*)d_in[0];
    const float* ln1w = (const float*)d_in[1];
    const float* ln1b = (const float*)d_in[2];
    const float* ln2w = (const float*)d_in[3];
    const float* ln2b = (const float*)d_in[4];
    const float* sc   = (const float*)d_in[5];
    const float* pre  = (const float*)d_in[6];
    const float* pim  = (const float*)d_in[7];
    const float* lre  = (const float*)d_in[8];
    const float* lim  = (const float*)d_in[9];
    const float* w1   = (const float*)d_in[10];
    const float* b1   = (const float*)d_in[11];
    const float* w2   = (const float*)d_in[12];
    const float* b2   = (const float*)d_in[13];

    char* ws = (char*)d_ws;
    float2*     st  = (float2*)(ws + ST_OFF);
    float2*     e   = (float2*)(ws + E_OFF);
    _Float16*   h2  = (_Float16*)(ws + H2_OFF);
    _Float16*   w1h = (_Float16*)(ws + W1H_OFF);
    _Float16*   w2h = (_Float16*)(ws + W2H_OFF);
    _Float16*   y1  = (_Float16*)(ws + Y1_OFF);
    float*      x2  = (float*)d_out;
    float*      outp = (float*)d_out;

    // blocks: 8192 stats + 4096 cast(w1) + 4096 cast(w2) = 16384
    prep<<<dim3(MROWS + 2 * CAST_BLKS), 256, 0, stream>>>(
        x, st, w1, w1h, w2, w2h);
    scan_partial<<<dim3(DIMD / 256, CHUNKS, BATCH), 256, 0, stream>>>(
        x, st, ln1w, ln1b, pre, pim, e);
    scan_final<<<dim3(DIMD / 256, CHUNKS, BATCH), 256, 0, stream>>>(
        x, st, ln1w, ln1b, pre, pim, sc, lre, lim, e, x2);
    ln_kernel<<<dim3(MROWS), 256, 0, stream>>>(x2, ln2w, ln2b, h2);
    gemm1_32<32><<<dim3(FFD / GBN, MROWS / GBM), 256, 0, stream>>>(
        h2, w1h, b1, y1, FFD, DIMD);
    gemm2_16<8><<<dim3(DIMD / GBN, MROWS / GBM), 256, 0, stream>>>(
        y1, w2h, b2, x2, outp, DIMD, FFD);
}